// Round 8
// baseline (235.476 us; speedup 1.0000x reference)
//
#include <hip/hip_runtime.h>

#define NCLS 91
#define NP (NCLS * NCLS)          // 8281 pair bins
#define NPPAD 8284                // /4-aligned for uint4 zeroing
#define NHIST (3 * NCLS)          // ws: cnt_in | cnt_tg | inter
#define BS 512
#define NBLK 4096

__global__ __launch_bounds__(BS, 8) void miou_hist(const float* __restrict__ inp,
                                                   const int* __restrict__ tgt,
                                                   unsigned int* __restrict__ ws,
                                                   int n4) {
    __shared__ unsigned int ph[NPPAD];   // 33,136 B -> 4 blocks/CU, 32 waves/CU
    uint4* z = (uint4*)ph;
    for (int i = threadIdx.x; i < NPPAD / 4; i += BS) z[i] = make_uint4(0u, 0u, 0u, 0u);
    __syncthreads();

    const float4* in4 = (const float4*)inp;
    const int4* tg4 = (const int4*)tgt;
    const int i0 = blockIdx.x * BS + threadIdx.x;
    const int stride = NBLK * BS;        // 2,097,152 threads -> 2 quads/thread

    // Both iterations' loads issued before any atomic (independent, tiny VGPR).
    if (i0 + stride < n4) {
        float4 f0 = in4[i0];
        int4  t0 = tg4[i0];
        float4 f1 = in4[i0 + stride];
        int4  t1 = tg4[i0 + stride];
        atomicAdd(&ph[(int)f0.x * NCLS + t0.x], 1u);
        atomicAdd(&ph[(int)f0.y * NCLS + t0.y], 1u);
        atomicAdd(&ph[(int)f0.z * NCLS + t0.z], 1u);
        atomicAdd(&ph[(int)f0.w * NCLS + t0.w], 1u);
        atomicAdd(&ph[(int)f1.x * NCLS + t1.x], 1u);
        atomicAdd(&ph[(int)f1.y * NCLS + t1.y], 1u);
        atomicAdd(&ph[(int)f1.z * NCLS + t1.z], 1u);
        atomicAdd(&ph[(int)f1.w * NCLS + t1.w], 1u);
    } else {
        for (int i = i0; i < n4; i += stride) {
            float4 f = in4[i];
            int4 t = tg4[i];
            atomicAdd(&ph[(int)f.x * NCLS + t.x], 1u);
            atomicAdd(&ph[(int)f.y * NCLS + t.y], 1u);
            atomicAdd(&ph[(int)f.z * NCLS + t.z], 1u);
            atomicAdd(&ph[(int)f.w * NCLS + t.w], 1u);
        }
    }
    __syncthreads();

    // Fold. Threads 0..90: row sums (cnt_in) + diagonal (inter). 128..218: col sums (cnt_tg).
    int t = threadIdx.x;
    if (t < NCLS) {
        const unsigned int* p = ph + t * NCLS;
        unsigned int s0 = 0, s1 = 0, s2 = 0, s3 = 0;
        int k = 0;
        for (; k + 3 < NCLS; k += 4) { s0 += p[k]; s1 += p[k+1]; s2 += p[k+2]; s3 += p[k+3]; }
        for (; k < NCLS; ++k) s0 += p[k];
        unsigned int s = s0 + s1 + s2 + s3;
        if (s) atomicAdd(&ws[t], s);
        unsigned int d = p[t];
        if (d) atomicAdd(&ws[2 * NCLS + t], d);
    } else if (t >= 128 && t < 128 + NCLS) {
        int c = t - 128;
        unsigned int s0 = 0, s1 = 0, s2 = 0, s3 = 0;
        int a = 0;
        for (; a + 3 < NCLS; a += 4) {
            s0 += ph[a * NCLS + c];
            s1 += ph[(a + 1) * NCLS + c];
            s2 += ph[(a + 2) * NCLS + c];
            s3 += ph[(a + 3) * NCLS + c];
        }
        for (; a < NCLS; ++a) s0 += ph[a * NCLS + c];
        unsigned int s = s0 + s1 + s2 + s3;
        if (s) atomicAdd(&ws[NCLS + c], s);
    }
}

// Generic tail (not launched for 64x512x512).
__global__ void miou_tail(const float* __restrict__ inp, const int* __restrict__ tgt,
                          unsigned int* __restrict__ ws, int e0, int n) {
    int i = e0 + blockIdx.x * 256 + threadIdx.x;
    if (i < n) {
        int a = (int)inp[i];
        int t = tgt[i];
        atomicAdd(&ws[a], 1u);
        atomicAdd(&ws[NCLS + t], 1u);
        if (a == t) atomicAdd(&ws[2 * NCLS + a], 1u);
    }
}

__global__ void miou_finalize(const unsigned int* __restrict__ ws,
                              const int* __restrict__ smooth_p,
                              float* __restrict__ out) {
    int lane = threadIdx.x;  // 64 threads
    float s = (float)(*smooth_p);
    float acc = 0.f;
    for (int c = 1 + lane; c < NCLS; c += 64) {
        float ci = (float)ws[c];
        float ct = (float)ws[NCLS + c];
        float it = (float)ws[2 * NCLS + c];
        float un = ci + ct - it;
        acc += (it + s) / (un + s);
    }
    #pragma unroll
    for (int off = 32; off; off >>= 1) acc += __shfl_down(acc, off);
    if (lane == 0) out[0] = acc / (float)(NCLS - 1);
}

extern "C" void kernel_launch(void* const* d_in, const int* in_sizes, int n_in,
                              void* d_out, int out_size, void* d_ws, size_t ws_size,
                              hipStream_t stream) {
    const float* inp = (const float*)d_in[0];
    const int* tgt = (const int*)d_in[1];
    const int* smooth_p = (const int*)d_in[2];
    float* out = (float*)d_out;
    unsigned int* ws = (unsigned int*)d_ws;

    int n = in_sizes[0];      // 16,777,216
    int n4 = n >> 2;          // 4,194,304 quads
    int e0 = (n4 & ~3) * 0 + (n & ~3);   // quads cover n rounded down to /4

    hipMemsetAsync(ws, 0, NHIST * sizeof(unsigned int), stream);
    miou_hist<<<NBLK, BS, 0, stream>>>(inp, tgt, ws, n4);
    if (e0 < n)
        miou_tail<<<(n - e0 + 255) / 256, 256, 0, stream>>>(inp, tgt, ws, e0, n);
    miou_finalize<<<1, 64, 0, stream>>>(ws, smooth_p, out);
}

// Round 9
// 159.396 us; speedup vs baseline: 1.4773x; 1.4773x over previous
//
#include <hip/hip_runtime.h>

#define NCLS 91
#define NPPAD 8284                // 91*91=8281 pair bins, /4-aligned
#define NHIST (3 * NCLS)          // ws: cnt_in | cnt_tg | inter
#define BS 256
#define NBLK 1024
#define U 8                       // quads per chunk (16 loads in flight)
#define NCHUNK 2                  // 2*8*4 = 64 elements per thread

__global__ __launch_bounds__(BS) void miou_hist(const float* __restrict__ inp,
                                                const int* __restrict__ tgt,
                                                unsigned int* __restrict__ ws,
                                                int n4) {
    __shared__ unsigned int ph[NPPAD];   // 33,136 B -> 4 blocks/CU
    uint4* z = (uint4*)ph;
    for (int i = threadIdx.x; i < NPPAD / 4; i += BS) z[i] = make_uint4(0u, 0u, 0u, 0u);
    __syncthreads();

    const float4* in4 = (const float4*)inp;
    const int4* tg4 = (const int4*)tgt;
    const int stride = NBLK * BS;                 // 262,144 quads
    const int i0 = blockIdx.x * BS + threadIdx.x;

    if (i0 + (NCHUNK * U - 1) * stride < n4) {
        #pragma unroll
        for (int c = 0; c < NCHUNK; ++c) {
            const int base = i0 + c * U * stride;
            float4 f[U];
            int4 t[U];
            // Issue ALL 16 loads...
            #pragma unroll
            for (int u = 0; u < U; ++u) {
                f[u] = in4[base + u * stride];
                t[u] = tg4[base + u * stride];
            }
            // ...then fence: nothing may sink below / hoist above. RA must keep
            // all 16 dwordx4 results live => 16 loads in flight per wave.
            __builtin_amdgcn_sched_barrier(0);
            #pragma unroll
            for (int u = 0; u < U; ++u) {
                atomicAdd(&ph[(int)f[u].x * NCLS + t[u].x], 1u);
                atomicAdd(&ph[(int)f[u].y * NCLS + t[u].y], 1u);
                atomicAdd(&ph[(int)f[u].z * NCLS + t[u].z], 1u);
                atomicAdd(&ph[(int)f[u].w * NCLS + t[u].w], 1u);
            }
        }
    } else {
        for (int i = i0; i < n4; i += stride) {
            float4 f = in4[i];
            int4 t = tg4[i];
            atomicAdd(&ph[(int)f.x * NCLS + t.x], 1u);
            atomicAdd(&ph[(int)f.y * NCLS + t.y], 1u);
            atomicAdd(&ph[(int)f.z * NCLS + t.z], 1u);
            atomicAdd(&ph[(int)f.w * NCLS + t.w], 1u);
        }
    }
    __syncthreads();

    // Fold. Threads 0..90: row sums (cnt_in) + diagonal (inter). 128..218: col sums (cnt_tg).
    int t = threadIdx.x;
    if (t < NCLS) {
        const unsigned int* p = ph + t * NCLS;
        unsigned int s0 = 0, s1 = 0, s2 = 0, s3 = 0;
        int k = 0;
        for (; k + 3 < NCLS; k += 4) { s0 += p[k]; s1 += p[k+1]; s2 += p[k+2]; s3 += p[k+3]; }
        for (; k < NCLS; ++k) s0 += p[k];
        unsigned int s = s0 + s1 + s2 + s3;
        if (s) atomicAdd(&ws[t], s);
        unsigned int d = p[t];
        if (d) atomicAdd(&ws[2 * NCLS + t], d);
    } else if (t >= 128 && t < 128 + NCLS) {
        int c = t - 128;
        unsigned int s0 = 0, s1 = 0, s2 = 0, s3 = 0;
        int a = 0;
        for (; a + 3 < NCLS; a += 4) {
            s0 += ph[a * NCLS + c];
            s1 += ph[(a + 1) * NCLS + c];
            s2 += ph[(a + 2) * NCLS + c];
            s3 += ph[(a + 3) * NCLS + c];
        }
        for (; a < NCLS; ++a) s0 += ph[a * NCLS + c];
        unsigned int s = s0 + s1 + s2 + s3;
        if (s) atomicAdd(&ws[NCLS + c], s);
    }
}

// Generic tail (not launched for 64x512x512).
__global__ void miou_tail(const float* __restrict__ inp, const int* __restrict__ tgt,
                          unsigned int* __restrict__ ws, int e0, int n) {
    int i = e0 + blockIdx.x * 256 + threadIdx.x;
    if (i < n) {
        int a = (int)inp[i];
        int t = tgt[i];
        atomicAdd(&ws[a], 1u);
        atomicAdd(&ws[NCLS + t], 1u);
        if (a == t) atomicAdd(&ws[2 * NCLS + a], 1u);
    }
}

__global__ void miou_finalize(const unsigned int* __restrict__ ws,
                              const int* __restrict__ smooth_p,
                              float* __restrict__ out) {
    int lane = threadIdx.x;  // 64 threads
    float s = (float)(*smooth_p);
    float acc = 0.f;
    for (int c = 1 + lane; c < NCLS; c += 64) {
        float ci = (float)ws[c];
        float ct = (float)ws[NCLS + c];
        float it = (float)ws[2 * NCLS + c];
        float un = ci + ct - it;
        acc += (it + s) / (un + s);
    }
    #pragma unroll
    for (int off = 32; off; off >>= 1) acc += __shfl_down(acc, off);
    if (lane == 0) out[0] = acc / (float)(NCLS - 1);
}

extern "C" void kernel_launch(void* const* d_in, const int* in_sizes, int n_in,
                              void* d_out, int out_size, void* d_ws, size_t ws_size,
                              hipStream_t stream) {
    const float* inp = (const float*)d_in[0];
    const int* tgt = (const int*)d_in[1];
    const int* smooth_p = (const int*)d_in[2];
    float* out = (float*)d_out;
    unsigned int* ws = (unsigned int*)d_ws;

    int n = in_sizes[0];      // 16,777,216
    int n4 = n >> 2;          // 4,194,304 quads = NBLK*BS*NCHUNK*U exactly
    int e0 = n & ~3;

    hipMemsetAsync(ws, 0, NHIST * sizeof(unsigned int), stream);
    miou_hist<<<NBLK, BS, 0, stream>>>(inp, tgt, ws, n4);
    if (e0 < n)
        miou_tail<<<(n - e0 + 255) / 256, 256, 0, stream>>>(inp, tgt, ws, e0, n);
    miou_finalize<<<1, 64, 0, stream>>>(ws, smooth_p, out);
}

// Round 10
// 157.352 us; speedup vs baseline: 1.4965x; 1.0130x over previous
//
#include <hip/hip_runtime.h>

#define NCLS 91
#define NPPAD 8284                // 91*91=8281 pair bins, /4-aligned
#define NHIST (3 * NCLS)          // ws: cnt_in | cnt_tg | inter
#define BS 256
#define NBLK 1024                 // 4 waves/block * 1024 = 4096 waves

typedef float __attribute__((ext_vector_type(4))) f32x4;
typedef int   __attribute__((ext_vector_type(4))) i32x4;

// Issue 8 global_load_dwordx4 in one asm block: the compiler cannot collapse,
// split, or spill this burst; all 8 results (64 VGPRs) stay live until read.
__device__ __forceinline__ void issue8(const f32x4* pf0, const f32x4* pf1,
                                       const f32x4* pf2, const f32x4* pf3,
                                       const i32x4* pt0, const i32x4* pt1,
                                       const i32x4* pt2, const i32x4* pt3,
                                       f32x4& F0, f32x4& F1, f32x4& F2, f32x4& F3,
                                       i32x4& T0, i32x4& T1, i32x4& T2, i32x4& T3) {
    asm volatile(
        "global_load_dwordx4 %0, %8, off\n\t"
        "global_load_dwordx4 %1, %9, off\n\t"
        "global_load_dwordx4 %2, %10, off\n\t"
        "global_load_dwordx4 %3, %11, off\n\t"
        "global_load_dwordx4 %4, %12, off\n\t"
        "global_load_dwordx4 %5, %13, off\n\t"
        "global_load_dwordx4 %6, %14, off\n\t"
        "global_load_dwordx4 %7, %15, off"
        : "=&v"(F0), "=&v"(F1), "=&v"(F2), "=&v"(F3),
          "=&v"(T0), "=&v"(T1), "=&v"(T2), "=&v"(T3)
        : "v"(pf0), "v"(pf1), "v"(pf2), "v"(pf3),
          "v"(pt0), "v"(pt1), "v"(pt2), "v"(pt3)
        : "memory");
}

__device__ __forceinline__ void proc16(unsigned int* __restrict__ ph,
                                       f32x4 F0, f32x4 F1, f32x4 F2, f32x4 F3,
                                       i32x4 T0, i32x4 T1, i32x4 T2, i32x4 T3) {
#define P1(F, T, c) atomicAdd(&ph[(int)F[c] * NCLS + T[c]], 1u)
#define P4(F, T) P1(F, T, 0); P1(F, T, 1); P1(F, T, 2); P1(F, T, 3)
    P4(F0, T0); P4(F1, T1); P4(F2, T2); P4(F3, T3);
#undef P4
#undef P1
}

#define WAITV(N)                                            \
    asm volatile("s_waitcnt vmcnt(" #N ")" ::: "memory");   \
    __builtin_amdgcn_sched_barrier(0)

// Specialized: n4 must equal NBLK*4 waves * 4 gens * 4 loads * 64 lanes.
__global__ __launch_bounds__(BS) void miou_hist(const float* __restrict__ inp,
                                                const int* __restrict__ tgt,
                                                unsigned int* __restrict__ ws) {
    __shared__ unsigned int ph[NPPAD];   // 33,136 B -> 4 blocks/CU (LDS-bound)
    uint4* z = (uint4*)ph;
    for (int i = threadIdx.x; i < NPPAD / 4; i += BS) z[i] = make_uint4(0u, 0u, 0u, 0u);
    __syncthreads();

    const int W = blockIdx.x * 4 + (threadIdx.x >> 6);   // global wave id
    const int lane = threadIdx.x & 63;
    const f32x4* fb = (const f32x4*)inp;
    const i32x4* tb = (const i32x4*)tgt;
    // gen g, load u: quad index = ((W*4+g)*4+u)*64 + lane  (4KB contiguous per load)
#define PF(g, u) (fb + (((W * 4 + (g)) * 4 + (u)) * 64 + lane))
#define PT(g, u) (tb + (((W * 4 + (g)) * 4 + (u)) * 64 + lane))

    f32x4 A0, A1, A2, A3, B0, B1, B2, B3;
    i32x4 A4, A5, A6, A7, B4, B5, B6, B7;

    issue8(PF(0,0), PF(0,1), PF(0,2), PF(0,3), PT(0,0), PT(0,1), PT(0,2), PT(0,3),
           A0, A1, A2, A3, A4, A5, A6, A7);
    issue8(PF(1,0), PF(1,1), PF(1,2), PF(1,3), PT(1,0), PT(1,1), PT(1,2), PT(1,3),
           B0, B1, B2, B3, B4, B5, B6, B7);
    WAITV(8);                                   // gen0 landed; gen1 in flight
    proc16(ph, A0, A1, A2, A3, A4, A5, A6, A7);
    issue8(PF(2,0), PF(2,1), PF(2,2), PF(2,3), PT(2,0), PT(2,1), PT(2,2), PT(2,3),
           A0, A1, A2, A3, A4, A5, A6, A7);
    WAITV(8);                                   // gen1 landed; gen2 in flight
    proc16(ph, B0, B1, B2, B3, B4, B5, B6, B7);
    issue8(PF(3,0), PF(3,1), PF(3,2), PF(3,3), PT(3,0), PT(3,1), PT(3,2), PT(3,3),
           B0, B1, B2, B3, B4, B5, B6, B7);
    WAITV(8);                                   // gen2 landed; gen3 in flight
    proc16(ph, A0, A1, A2, A3, A4, A5, A6, A7);
    WAITV(0);                                   // gen3 landed
    proc16(ph, B0, B1, B2, B3, B4, B5, B6, B7);
#undef PF
#undef PT
    __syncthreads();

    // Fold. Threads 0..90: row sums (cnt_in) + diagonal (inter). 128..218: col sums (cnt_tg).
    int t = threadIdx.x;
    if (t < NCLS) {
        const unsigned int* p = ph + t * NCLS;
        unsigned int s0 = 0, s1 = 0, s2 = 0, s3 = 0;
        int k = 0;
        for (; k + 3 < NCLS; k += 4) { s0 += p[k]; s1 += p[k+1]; s2 += p[k+2]; s3 += p[k+3]; }
        for (; k < NCLS; ++k) s0 += p[k];
        unsigned int s = s0 + s1 + s2 + s3;
        if (s) atomicAdd(&ws[t], s);
        unsigned int d = p[t];
        if (d) atomicAdd(&ws[2 * NCLS + t], d);
    } else if (t >= 128 && t < 128 + NCLS) {
        int c = t - 128;
        unsigned int s0 = 0, s1 = 0, s2 = 0, s3 = 0;
        int a = 0;
        for (; a + 3 < NCLS; a += 4) {
            s0 += ph[a * NCLS + c];
            s1 += ph[(a + 1) * NCLS + c];
            s2 += ph[(a + 2) * NCLS + c];
            s3 += ph[(a + 3) * NCLS + c];
        }
        for (; a < NCLS; ++a) s0 += ph[a * NCLS + c];
        unsigned int s = s0 + s1 + s2 + s3;
        if (s) atomicAdd(&ws[NCLS + c], s);
    }
}

// Generic fallback for any shape.
__global__ __launch_bounds__(BS) void miou_hist_generic(const float* __restrict__ inp,
                                                        const int* __restrict__ tgt,
                                                        unsigned int* __restrict__ ws,
                                                        int n) {
    __shared__ unsigned int ph[NPPAD];
    uint4* z = (uint4*)ph;
    for (int i = threadIdx.x; i < NPPAD / 4; i += BS) z[i] = make_uint4(0u, 0u, 0u, 0u);
    __syncthreads();
    int stride = gridDim.x * BS;
    for (int i = blockIdx.x * BS + threadIdx.x; i < n; i += stride) {
        int a = (int)inp[i];
        int t = tgt[i];
        atomicAdd(&ph[a * NCLS + t], 1u);
    }
    __syncthreads();
    int t = threadIdx.x;
    if (t < NCLS) {
        const unsigned int* p = ph + t * NCLS;
        unsigned int s = 0;
        for (int k = 0; k < NCLS; ++k) s += p[k];
        if (s) atomicAdd(&ws[t], s);
        unsigned int d = p[t];
        if (d) atomicAdd(&ws[2 * NCLS + t], d);
    } else if (t >= 128 && t < 128 + NCLS) {
        int c = t - 128;
        unsigned int s = 0;
        for (int a = 0; a < NCLS; ++a) s += ph[a * NCLS + c];
        if (s) atomicAdd(&ws[NCLS + c], s);
    }
}

__global__ void miou_finalize(const unsigned int* __restrict__ ws,
                              const int* __restrict__ smooth_p,
                              float* __restrict__ out) {
    int lane = threadIdx.x;  // 64 threads
    float s = (float)(*smooth_p);
    float acc = 0.f;
    for (int c = 1 + lane; c < NCLS; c += 64) {
        float ci = (float)ws[c];
        float ct = (float)ws[NCLS + c];
        float it = (float)ws[2 * NCLS + c];
        float un = ci + ct - it;
        acc += (it + s) / (un + s);
    }
    #pragma unroll
    for (int off = 32; off; off >>= 1) acc += __shfl_down(acc, off);
    if (lane == 0) out[0] = acc / (float)(NCLS - 1);
}

extern "C" void kernel_launch(void* const* d_in, const int* in_sizes, int n_in,
                              void* d_out, int out_size, void* d_ws, size_t ws_size,
                              hipStream_t stream) {
    const float* inp = (const float*)d_in[0];
    const int* tgt = (const int*)d_in[1];
    const int* smooth_p = (const int*)d_in[2];
    float* out = (float*)d_out;
    unsigned int* ws = (unsigned int*)d_ws;

    int n = in_sizes[0];
    hipMemsetAsync(ws, 0, NHIST * sizeof(unsigned int), stream);
    if (n == NBLK * 4 * 4 * 4 * 64 * 4) {       // 16,777,216: specialized path
        miou_hist<<<NBLK, BS, 0, stream>>>(inp, tgt, ws);
    } else {
        miou_hist_generic<<<1024, BS, 0, stream>>>(inp, tgt, ws, n);
    }
    miou_finalize<<<1, 64, 0, stream>>>(ws, smooth_p, out);
}

// Round 12
// 154.573 us; speedup vs baseline: 1.5234x; 1.0180x over previous
//
#include <hip/hip_runtime.h>

#define NCLS 91
#define TPB 256                    // threads per block = private columns
#define NSHARD 8
#define BS 256
#define NBLK 512
#define GENS 8

typedef float __attribute__((ext_vector_type(4))) f32x4;
typedef int   __attribute__((ext_vector_type(4))) i32x4;

__device__ __forceinline__ void issue8(const f32x4* pf0, const f32x4* pf1,
                                       const f32x4* pf2, const f32x4* pf3,
                                       const i32x4* pt0, const i32x4* pt1,
                                       const i32x4* pt2, const i32x4* pt3,
                                       f32x4& F0, f32x4& F1, f32x4& F2, f32x4& F3,
                                       i32x4& T0, i32x4& T1, i32x4& T2, i32x4& T3) {
    asm volatile(
        "global_load_dwordx4 %0, %8, off\n\t"
        "global_load_dwordx4 %1, %9, off\n\t"
        "global_load_dwordx4 %2, %10, off\n\t"
        "global_load_dwordx4 %3, %11, off\n\t"
        "global_load_dwordx4 %4, %12, off\n\t"
        "global_load_dwordx4 %5, %13, off\n\t"
        "global_load_dwordx4 %6, %14, off\n\t"
        "global_load_dwordx4 %7, %15, off"
        : "=&v"(F0), "=&v"(F1), "=&v"(F2), "=&v"(F3),
          "=&v"(T0), "=&v"(T1), "=&v"(T2), "=&v"(T3)
        : "v"(pf0), "v"(pf1), "v"(pf2), "v"(pf3),
          "v"(pt0), "v"(pt1), "v"(pt2), "v"(pt3)
        : "memory");
}

// Race-free RMW: each thread owns column `tid` of every class row.
__device__ __forceinline__ void rmw16(unsigned short* __restrict__ h16,
                                      unsigned char* __restrict__ tg8, int tid,
                                      f32x4 F0, f32x4 F1, f32x4 F2, f32x4 F3,
                                      i32x4 T0, i32x4 T1, i32x4 T2, i32x4 T3) {
#define E1(F, Tv, c)                                                          \
    {                                                                         \
        int a = (int)F[c];                                                    \
        int tv = Tv[c];                                                       \
        h16[a * TPB + tid] =                                                  \
            (unsigned short)(h16[a * TPB + tid] + 1u + ((a == tv) << 8));     \
        tg8[tv * TPB + tid] = (unsigned char)(tg8[tv * TPB + tid] + 1u);      \
    }
#define E4(F, Tv) E1(F, Tv, 0) E1(F, Tv, 1) E1(F, Tv, 2) E1(F, Tv, 3)
    E4(F0, T0) E4(F1, T1) E4(F2, T2) E4(F3, T3)
#undef E4
#undef E1
}

#define WAITV(N)                                            \
    asm volatile("s_waitcnt vmcnt(" #N ")" ::: "memory");   \
    __builtin_amdgcn_sched_barrier(0)

// Specialized for n = NBLK*4 waves * GENS * 4 loads * 64 lanes * 4 = 16,777,216.
__global__ __launch_bounds__(BS) void miou_hist(const float* __restrict__ inp,
                                                const int* __restrict__ tgt,
                                                unsigned int* __restrict__ ws) {
    __shared__ unsigned short h16[NCLS * TPB];   // [class][thread] lo=cnt_in hi=inter
    __shared__ unsigned char  tg8[NCLS * TPB];   // [class][thread] cnt_tg
    uint4* z1 = (uint4*)h16;
    uint4* z2 = (uint4*)tg8;
    for (int i = threadIdx.x; i < NCLS * TPB * 2 / 16; i += BS) z1[i] = make_uint4(0,0,0,0);
    for (int i = threadIdx.x; i < NCLS * TPB / 16; i += BS) z2[i] = make_uint4(0,0,0,0);
    __syncthreads();

    const int tid = threadIdx.x;
    const int W = blockIdx.x * 4 + (tid >> 6);
    const int lane = tid & 63;
    const f32x4* fb = (const f32x4*)inp;
    const i32x4* tb = (const i32x4*)tgt;
#define PF(g, u) (fb + (((W * GENS + (g)) * 4 + (u)) * 64 + lane))
#define PT(g, u) (tb + (((W * GENS + (g)) * 4 + (u)) * 64 + lane))
#define ISSUE(BK, g) issue8(PF(g,0), PF(g,1), PF(g,2), PF(g,3),               \
                            PT(g,0), PT(g,1), PT(g,2), PT(g,3),               \
                            BK##0, BK##1, BK##2, BK##3, BK##4, BK##5, BK##6, BK##7)
#define PROC(BK) rmw16(h16, tg8, tid, BK##0, BK##1, BK##2, BK##3, BK##4, BK##5, BK##6, BK##7)

    f32x4 A0, A1, A2, A3, B0, B1, B2, B3;
    i32x4 A4, A5, A6, A7, B4, B5, B6, B7;

    ISSUE(A, 0); ISSUE(B, 1);
    WAITV(8); PROC(A); ISSUE(A, 2);
    WAITV(8); PROC(B); ISSUE(B, 3);
    WAITV(8); PROC(A); ISSUE(A, 4);
    WAITV(8); PROC(B); ISSUE(B, 5);
    WAITV(8); PROC(A); ISSUE(A, 6);
    WAITV(8); PROC(B); ISSUE(B, 7);
    WAITV(8); PROC(A);
    WAITV(0); PROC(B);
#undef PF
#undef PT
#undef ISSUE
#undef PROC
    __syncthreads();

    // Fold rows; push per-block sums to one of 8 global shards.
    const int shard = (blockIdx.x & (NSHARD - 1)) * 3 * NCLS;
    int t = threadIdx.x;
    if (t < NCLS) {
        const uint4* row = (const uint4*)&h16[t * TPB];   // 256 u16 = 32 uint4
        unsigned int cin = 0, cit = 0;
        #pragma unroll 4
        for (int k = 0; k < 32; ++k) {
            uint4 v = row[k];
            unsigned int d;
            d = v.x; cin += (d & 0xFFu) + ((d >> 16) & 0xFFu); cit += ((d >> 8) & 0xFFu) + (d >> 24);
            d = v.y; cin += (d & 0xFFu) + ((d >> 16) & 0xFFu); cit += ((d >> 8) & 0xFFu) + (d >> 24);
            d = v.z; cin += (d & 0xFFu) + ((d >> 16) & 0xFFu); cit += ((d >> 8) & 0xFFu) + (d >> 24);
            d = v.w; cin += (d & 0xFFu) + ((d >> 16) & 0xFFu); cit += ((d >> 8) & 0xFFu) + (d >> 24);
        }
        if (cin) atomicAdd(&ws[shard + t], cin);
        if (cit) atomicAdd(&ws[shard + 2 * NCLS + t], cit);
    } else if (t >= 128 && t < 128 + NCLS) {
        int c = t - 128;
        const uint4* row = (const uint4*)&tg8[c * TPB];   // 256 u8 = 16 uint4
        unsigned int s = 0;
        #pragma unroll 4
        for (int k = 0; k < 16; ++k) {
            uint4 v = row[k];
            unsigned int d;
            d = v.x; s += (d & 0xFFu) + ((d >> 8) & 0xFFu) + ((d >> 16) & 0xFFu) + (d >> 24);
            d = v.y; s += (d & 0xFFu) + ((d >> 8) & 0xFFu) + ((d >> 16) & 0xFFu) + (d >> 24);
            d = v.z; s += (d & 0xFFu) + ((d >> 8) & 0xFFu) + ((d >> 16) & 0xFFu) + (d >> 24);
            d = v.w; s += (d & 0xFFu) + ((d >> 8) & 0xFFu) + ((d >> 16) & 0xFFu) + (d >> 24);
        }
        if (s) atomicAdd(&ws[shard + NCLS + c], s);
    }
}

// Generic fallback for any shape (correctness path; writes shard 0).
__global__ __launch_bounds__(BS) void miou_hist_generic(const float* __restrict__ inp,
                                                        const int* __restrict__ tgt,
                                                        unsigned int* __restrict__ ws,
                                                        int n) {
    __shared__ unsigned int ph[NCLS * NCLS + 3];
    uint4* z = (uint4*)ph;
    for (int i = threadIdx.x; i < (NCLS * NCLS + 3) / 4; i += BS) z[i] = make_uint4(0,0,0,0);
    __syncthreads();
    int stride = gridDim.x * BS;
    for (int i = blockIdx.x * BS + threadIdx.x; i < n; i += stride) {
        int a = (int)inp[i];
        int t = tgt[i];
        atomicAdd(&ph[a * NCLS + t], 1u);
    }
    __syncthreads();
    int t = threadIdx.x;
    if (t < NCLS) {
        unsigned int s = 0;
        for (int k = 0; k < NCLS; ++k) s += ph[t * NCLS + k];
        if (s) atomicAdd(&ws[t], s);
        unsigned int d = ph[t * NCLS + t];
        if (d) atomicAdd(&ws[2 * NCLS + t], d);
    } else if (t >= 128 && t < 128 + NCLS) {
        int c = t - 128;
        unsigned int s = 0;
        for (int a = 0; a < NCLS; ++a) s += ph[a * NCLS + c];
        if (s) atomicAdd(&ws[NCLS + c], s);
    }
}

__global__ void miou_finalize(const unsigned int* __restrict__ ws,
                              const int* __restrict__ smooth_p,
                              float* __restrict__ out) {
    int lane = threadIdx.x;  // 64 threads
    float s = (float)(*smooth_p);
    float acc = 0.f;
    for (int c = 1 + lane; c < NCLS; c += 64) {
        float ci = 0.f, ct = 0.f, it = 0.f;
        #pragma unroll
        for (int sh = 0; sh < NSHARD; ++sh) {
            ci += (float)ws[sh * 3 * NCLS + c];
            ct += (float)ws[sh * 3 * NCLS + NCLS + c];
            it += (float)ws[sh * 3 * NCLS + 2 * NCLS + c];
        }
        acc += (it + s) / (ci + ct - it + s);
    }
    #pragma unroll
    for (int off = 32; off; off >>= 1) acc += __shfl_down(acc, off);
    if (lane == 0) out[0] = acc / (float)(NCLS - 1);
}

extern "C" void kernel_launch(void* const* d_in, const int* in_sizes, int n_in,
                              void* d_out, int out_size, void* d_ws, size_t ws_size,
                              hipStream_t stream) {
    const float* inp = (const float*)d_in[0];
    const int* tgt = (const int*)d_in[1];
    const int* smooth_p = (const int*)d_in[2];
    float* out = (float*)d_out;
    unsigned int* ws = (unsigned int*)d_ws;

    int n = in_sizes[0];
    hipMemsetAsync(ws, 0, NSHARD * 3 * NCLS * sizeof(unsigned int), stream);
    if (n == NBLK * 4 * GENS * 4 * 64 * 4) {     // 16,777,216: fast path
        miou_hist<<<NBLK, BS, 0, stream>>>(inp, tgt, ws);
    } else {
        miou_hist_generic<<<1024, BS, 0, stream>>>(inp, tgt, ws, n);
    }
    miou_finalize<<<1, 64, 0, stream>>>(ws, smooth_p, out);
}